// Round 6
// baseline (542.142 us; speedup 1.0000x reference)
//
#include <hip/hip_runtime.h>
#include <math.h>

// Problem constants
#define NCOL 32768          // N = 32*32*32 columns
#define KAT  512            // dictionary atoms
#define DIM  64             // embedding dim

// Output flat offsets (fp32 elements)
#define O_LOSS  0
#define O_RECON 1
#define O_ZF    2097153     // 1 + 2097152
#define O_PERP  4194305
#define O_GAMMA 4194306

// Workspace layout (fp32 elements)
#define WS_DN   0           // Dn  [64][512]
#define WS_DNT  32768       // DnT [512][64]
#define WS_G    65536       // G   [512][512]
#define WS_ACC  327680      // acc[0]=sum sq, acc[1]=sum S, acc[2]=block counter

// ---------------------------------------------------------------------------
// DPP wave-64 reductions (all-VALU; result broadcast via readlane)
__device__ __forceinline__ float wave_max_bcast_f32(float v) {
    int x = __float_as_int(v);
    int t;
    t = __builtin_amdgcn_update_dpp(x, x, 0x111, 0xf, 0xf, false);  // row_shr:1
    x = __float_as_int(fmaxf(__int_as_float(x), __int_as_float(t)));
    t = __builtin_amdgcn_update_dpp(x, x, 0x112, 0xf, 0xf, false);  // row_shr:2
    x = __float_as_int(fmaxf(__int_as_float(x), __int_as_float(t)));
    t = __builtin_amdgcn_update_dpp(x, x, 0x114, 0xf, 0xf, false);  // row_shr:4
    x = __float_as_int(fmaxf(__int_as_float(x), __int_as_float(t)));
    t = __builtin_amdgcn_update_dpp(x, x, 0x118, 0xf, 0xf, false);  // row_shr:8
    x = __float_as_int(fmaxf(__int_as_float(x), __int_as_float(t)));
    t = __builtin_amdgcn_update_dpp(x, x, 0x142, 0xa, 0xf, false);  // row_bcast:15
    x = __float_as_int(fmaxf(__int_as_float(x), __int_as_float(t)));
    t = __builtin_amdgcn_update_dpp(x, x, 0x143, 0xc, 0xf, false);  // row_bcast:31
    x = __float_as_int(fmaxf(__int_as_float(x), __int_as_float(t)));
    return __int_as_float(__builtin_amdgcn_readlane(x, 63));
}

__device__ __forceinline__ unsigned wave_min_bcast_u32(unsigned v) {
    int x = (int)v;
    int t;
    t = __builtin_amdgcn_update_dpp(x, x, 0x111, 0xf, 0xf, false);
    x = (int)min((unsigned)x, (unsigned)t);
    t = __builtin_amdgcn_update_dpp(x, x, 0x112, 0xf, 0xf, false);
    x = (int)min((unsigned)x, (unsigned)t);
    t = __builtin_amdgcn_update_dpp(x, x, 0x114, 0xf, 0xf, false);
    x = (int)min((unsigned)x, (unsigned)t);
    t = __builtin_amdgcn_update_dpp(x, x, 0x118, 0xf, 0xf, false);
    x = (int)min((unsigned)x, (unsigned)t);
    t = __builtin_amdgcn_update_dpp(x, x, 0x142, 0xa, 0xf, false);
    x = (int)min((unsigned)x, (unsigned)t);
    t = __builtin_amdgcn_update_dpp(x, x, 0x143, 0xc, 0xf, false);
    x = (int)min((unsigned)x, (unsigned)t);
    return (unsigned)__builtin_amdgcn_readlane(x, 63);
}

// ---------------------------------------------------------------------------
// Kernel 1: gamma zero-fill (all 8192 blocks) + block 0: dict normalize + acc init.
__global__ __launch_bounds__(256) void init_kernel(const float* __restrict__ dict,
                                                   float* __restrict__ ws,
                                                   float* __restrict__ out) {
    int id = blockIdx.x * 256 + threadIdx.x;
    float2* g2 = (float2*)(out + O_GAMMA);      // 8B-aligned region
    #pragma unroll
    for (int i = 0; i < 4; ++i)
        g2[id + i * 2097152] = make_float2(0.f, 0.f);

    if (blockIdx.x == 0) {
        float* Dn  = ws + WS_DN;
        float* DnT = ws + WS_DNT;
        float* acc = ws + WS_ACC;
        int t = threadIdx.x;
        if (t == 0) { acc[0] = 0.f; acc[1] = 0.f; ((unsigned*)acc)[2] = 0u; }
        #pragma unroll
        for (int half = 0; half < 2; ++half) {
            int a = t + half * 256;
            float s = 0.f;
            #pragma unroll
            for (int d = 0; d < DIM; ++d) { float v = dict[d*KAT + a]; s += v * v; }
            float nrm = sqrtf(s);
            #pragma unroll
            for (int d = 0; d < DIM; ++d) {
                float v = dict[d*KAT + a] / nrm;
                Dn[d*KAT + a]  = v;
                DnT[a*DIM + d] = v;
            }
        }
    }
}

// ---------------------------------------------------------------------------
// Kernel 2: G = Dn^T Dn.  block = row i (512 blocks), thread = col j (512).
__global__ void gram_kernel(const float* __restrict__ ws_in, float* __restrict__ ws) {
    const float* Dn = ws_in + WS_DN;
    float* G = ws + WS_G;
    int i = blockIdx.x, j = threadIdx.x;
    float s = 0.f;
    #pragma unroll
    for (int d = 0; d < DIM; ++d)
        s = fmaf(Dn[d*KAT + i], Dn[d*KAT + j], s);
    G[i*KAT + j] = s;
}

// ---------------------------------------------------------------------------
// Kernel 3: fused zf-echo + h_bar + Batch-OMP (2 columns interleaved per wave)
// + last-block scalar finalize. 16 columns per 256-thread block.
__global__ __launch_bounds__(256, 2) void omp_kernel(const float* __restrict__ z_e,
                                                     const float* __restrict__ ws,
                                                     float* __restrict__ out,
                                                     const float* __restrict__ beta,
                                                     float* __restrict__ wsw) {
    const float* Dn  = ws + WS_DN;
    const float* DnT = ws + WS_DNT;
    const float* G   = ws + WS_G;
    float* acc = wsw + WS_ACC;

    __shared__ float xcols[DIM * 16];     // [d][c]  4 KB
    __shared__ float hbar[16 * KAT];      // [c][a] 32 KB

    const int t = threadIdx.x;
    const int n_base = blockIdx.x * 16;

    // ---- Phase 1: gather data columns; echo to zf output region
    #pragma unroll
    for (int i = 0; i < 4; ++i) {
        int e = t + i * 256;              // 0..1023
        int d = e >> 4, c = e & 15;
        int Lf = d * NCOL + n_base + c;
        int src = (Lf >> 16) * 65536 + (Lf & 63) * 1024 + (((Lf >> 11) & 31) << 5) + ((Lf >> 6) & 31);
        float v = z_e[src];
        xcols[e] = v;
        out[O_ZF + Lf] = v;
    }
    __syncthreads();

    // ---- Phase 2: h_bar tile (Dn read once per block)
    {
        float a0[16], a1[16];
        #pragma unroll
        for (int i = 0; i < 16; ++i) { a0[i] = 0.f; a1[i] = 0.f; }
        const float4* xc4 = (const float4*)xcols;
        for (int d = 0; d < DIM; ++d) {
            float v0 = Dn[d * KAT + t];
            float v1 = Dn[d * KAT + 256 + t];
            #pragma unroll
            for (int q = 0; q < 4; ++q) {
                float4 xv = xc4[d * 4 + q];
                a0[q*4+0] = fmaf(v0, xv.x, a0[q*4+0]);
                a0[q*4+1] = fmaf(v0, xv.y, a0[q*4+1]);
                a0[q*4+2] = fmaf(v0, xv.z, a0[q*4+2]);
                a0[q*4+3] = fmaf(v0, xv.w, a0[q*4+3]);
                a1[q*4+0] = fmaf(v1, xv.x, a1[q*4+0]);
                a1[q*4+1] = fmaf(v1, xv.y, a1[q*4+1]);
                a1[q*4+2] = fmaf(v1, xv.z, a1[q*4+2]);
                a1[q*4+3] = fmaf(v1, xv.w, a1[q*4+3]);
            }
        }
        #pragma unroll
        for (int c = 0; c < 16; ++c) {
            hbar[c * KAT + t]       = a0[c];
            hbar[c * KAT + 256 + t] = a1[c];
        }
    }
    __syncthreads();

    // ---- Phase 3: OMP, one wave per column-PAIR, 2 pairs sequentially
    const int wv = t >> 6, lane = t & 63;
    float wv_sq = 0.f, wv_S = 0.f;

    #pragma unroll 1
    for (int pp = 0; pp < 2; ++pp) {
        const int col0 = wv * 4 + pp * 2;

        float h[2][8];
        unsigned msk[2] = {0u, 0u};
        float uv[2][56], Lr[2][28], invd[2][8], yv[2][8], xr[2][8];
        int Iv[2][8];

        #pragma unroll
        for (int q = 0; q < 2; ++q)
            #pragma unroll
            for (int r = 0; r < 8; ++r)
                h[q][r] = hbar[(col0 + q) * KAT + (r << 6) + lane];

        #pragma unroll
        for (int k = 0; k < 8; ++k) {
            // local argmax over each column's 8 slots (track signed winner)
            float bv[2]; int bi[2]; float hb[2];
            #pragma unroll
            for (int q = 0; q < 2; ++q) {
                bv[q] = -1.f; bi[q] = 0; hb[q] = 0.f;
                #pragma unroll
                for (int r = 0; r < 8; ++r) {
                    float av = ((msk[q] >> r) & 1) ? -1.f : fabsf(h[q][r]);
                    bool gt = av > bv[q];
                    bv[q] = gt ? av : bv[q];
                    bi[q] = gt ? ((r << 6) | lane) : bi[q];
                    hb[q] = gt ? h[q][r] : hb[q];
                }
            }
            // two independent DPP trees interleave in the scheduler
            float maxv[2];
            maxv[0] = wave_max_bcast_f32(bv[0]);
            maxv[1] = wave_max_bcast_f32(bv[1]);
            unsigned cand0 = (bv[0] == maxv[0]) ? (unsigned)bi[0] : 0xffffffffu;
            unsigned cand1 = (bv[1] == maxv[1]) ? (unsigned)bi[1] : 0xffffffffu;
            int idx[2];
            idx[0] = (int)wave_min_bcast_u32(cand0);
            idx[1] = (int)wave_min_bcast_u32(cand1);

            float hwin[2], gk[2][8];
            const float* grow[2];
            #pragma unroll
            for (int q = 0; q < 2; ++q) {
                unsigned long long sm =
                    __ballot((bv[q] == maxv[q]) && (bi[q] == idx[q]) && (hb[q] < 0.f));
                hwin[q] = (sm != 0ull) ? -maxv[q] : maxv[q];
                if ((idx[q] & 63) == lane) msk[q] |= 1u << (idx[q] >> 6);
                Iv[q][k] = idx[q];
                grow[q] = G + idx[q] * KAT;
                if (k < 7) {
                    #pragma unroll
                    for (int r = 0; r < 8; ++r) gk[q][r] = grow[q][(r << 6) + lane];
                }
            }

            // replicated Cholesky rank-1 extension + u/h update (per column)
            #pragma unroll
            for (int q = 0; q < 2; ++q) {
                float Lk[7];
                if (k == 0) {
                    invd[q][0] = 1.f;
                } else {
                    float s2 = 0.f;
                    #pragma unroll
                    for (int i = 0; i < 7; ++i) if (i < k) {
                        float a = grow[q][Iv[q][i]];        // == G[Iv[i]][idx]
                        #pragma unroll
                        for (int j = 0; j < 7; ++j) if (j < i)
                            a = fmaf(-Lr[q][i*(i-1)/2 + j], Lk[j], a);
                        Lk[i] = a * invd[q][i];
                        s2 = fmaf(Lk[i], Lk[i], s2);
                    }
                    #pragma unroll
                    for (int j = 0; j < 7; ++j) if (j < k) Lr[q][k*(k-1)/2 + j] = Lk[j];
                    invd[q][k] = 1.f / sqrtf(1.f - s2);
                }
                yv[q][k] = hwin[q] * invd[q][k];

                if (k < 7) {
                    #pragma unroll
                    for (int r = 0; r < 8; ++r) {
                        float a = gk[q][r];
                        #pragma unroll
                        for (int j = 0; j < 7; ++j) if (j < k)
                            a = fmaf(-Lk[j], uv[q][j*8 + r], a);
                        a *= invd[q][k];
                        uv[q][k*8 + r] = a;
                        h[q][r] = fmaf(-yv[q][k], a, h[q][r]);
                    }
                }
            }
        }

        // backsolves + outputs
        #pragma unroll
        for (int q = 0; q < 2; ++q) {
            #pragma unroll
            for (int i = 7; i >= 0; --i) {
                float a = yv[q][i];
                #pragma unroll
                for (int j = 0; j < 8; ++j) if (j > i)
                    a = fmaf(-Lr[q][j*(j-1)/2 + i], xr[q][j], a);
                xr[q][i] = a * invd[q][i];
            }
            const int n = n_base + col0 + q;

            #pragma unroll
            for (int j = 0; j < 8; ++j)
                if (lane == j) out[O_GAMMA + Iv[q][j] * NCOL + n] = xr[q][j];

            float rec = 0.f;
            #pragma unroll
            for (int j = 0; j < 8; ++j)
                rec = fmaf(xr[q][j], DnT[Iv[q][j] * DIM + lane], rec);
            int Lf = lane * NCOL + n;
            int perm = (Lf >> 16) * 65536 + (Lf & 63) * 1024 + (((Lf >> 11) & 31) << 5) + ((Lf >> 6) & 31);
            out[O_RECON + perm] = rec;

            float xd = xcols[lane * 16 + col0 + q];
            float diff = rec - xd;
            float sq = diff * diff;
            #pragma unroll
            for (int off = 32; off; off >>= 1) sq += __shfl_xor(sq, off, 64);
            if (lane == 0) wv_sq += sq;

            // softmax-entropy: 8 nnz + 504 zeros, parallel over lanes 0..7
            {
                float m = 0.f;
                #pragma unroll
                for (int j = 0; j < 8; ++j) m = fmaxf(m, xr[q][j]);
                float xsel = 0.f;
                #pragma unroll
                for (int j = 0; j < 8; ++j) xsel = (lane == j) ? xr[q][j] : xsel;
                float e = (lane < 8) ? expf(xsel - m) : 0.f;
                float se = e;
                #pragma unroll
                for (int off = 1; off < 8; off <<= 1) se += __shfl_xor(se, off, 64);
                float e0 = expf(-m);
                float Z = fmaf(504.f, e0, se);       // valid on lanes 0..7
                float invZ = 1.f / Z;
                float p = e * invZ;
                float tq = (lane < 8) ? p * logf(p + 1e-10f) : 0.f;
                #pragma unroll
                for (int off = 1; off < 8; off <<= 1) tq += __shfl_xor(tq, off, 64);
                if (lane == 0) {
                    float p0 = e0 * invZ;
                    wv_S += tq + 504.f * p0 * logf(p0 + 1e-10f);
                }
            }
        }
    }

    if (lane == 0) {
        atomicAdd(&acc[0], wv_sq);
        atomicAdd(&acc[1], wv_S);
    }
    __threadfence();            // release: acc adds visible before counter bump
    __syncthreads();
    if (t == 0) {
        unsigned old = atomicAdd((unsigned*)acc + 2, 1u);
        if (old == gridDim.x - 1) {                 // last block finalizes
            __threadfence();                        // acquire
            float s0 = atomicAdd(&acc[0], 0.f);     // coherent L2 reads
            float s1 = atomicAdd(&acc[1], 0.f);
            float mse = s0 / 2097152.f;
            out[O_LOSS] = mse * 0.25f + beta[0] * mse;
            out[O_PERP] = expf(-s1 / 32768.f);
        }
    }
}

// ---------------------------------------------------------------------------
extern "C" void kernel_launch(void* const* d_in, const int* in_sizes, int n_in,
                              void* d_out, int out_size, void* d_ws, size_t ws_size,
                              hipStream_t stream) {
    const float* z_e  = (const float*)d_in[0];
    const float* dict = (const float*)d_in[1];
    const float* beta = (const float*)d_in[2];
    float* out = (float*)d_out;
    float* ws  = (float*)d_ws;

    init_kernel<<<8192, 256, 0, stream>>>(dict, ws, out);
    gram_kernel<<<512, 512, 0, stream>>>(ws, ws);
    omp_kernel<<<2048, 256, 0, stream>>>(z_e, ws, out, beta, ws);
}

// Round 7
// 521.460 us; speedup vs baseline: 1.0397x; 1.0397x over previous
//
#include <hip/hip_runtime.h>
#include <math.h>

// Problem constants
#define NCOL 32768          // N = 32*32*32 columns
#define KAT  512            // dictionary atoms
#define DIM  64             // embedding dim

// Output flat offsets (fp32 elements)
#define O_LOSS  0
#define O_RECON 1
#define O_ZF    2097153     // 1 + 2097152
#define O_PERP  4194305
#define O_GAMMA 4194306

// Workspace layout (fp32 elements)
#define WS_DN   0           // Dn  [64][512]
#define WS_DNT  32768       // DnT [512][64]
#define WS_G    65536       // G   [512][512]
#define WS_ACC  327680      // acc[0]=sum sq, acc[1]=sum S, acc[2]=block counter
#define WS_XT   327696      // xT  [32768][64]   (8 MB)
#define WS_HB   2424848     // h_bar [32768][512] (64 MB)
#define WS_NEED (19202064ull * 4ull)   // bytes required for the split path

// ---------------------------------------------------------------------------
// DPP wave-64 reductions (all-VALU; result broadcast via readlane)
__device__ __forceinline__ float wave_max_bcast_f32(float v) {
    int x = __float_as_int(v);
    int t;
    t = __builtin_amdgcn_update_dpp(x, x, 0x111, 0xf, 0xf, false);  // row_shr:1
    x = __float_as_int(fmaxf(__int_as_float(x), __int_as_float(t)));
    t = __builtin_amdgcn_update_dpp(x, x, 0x112, 0xf, 0xf, false);  // row_shr:2
    x = __float_as_int(fmaxf(__int_as_float(x), __int_as_float(t)));
    t = __builtin_amdgcn_update_dpp(x, x, 0x114, 0xf, 0xf, false);  // row_shr:4
    x = __float_as_int(fmaxf(__int_as_float(x), __int_as_float(t)));
    t = __builtin_amdgcn_update_dpp(x, x, 0x118, 0xf, 0xf, false);  // row_shr:8
    x = __float_as_int(fmaxf(__int_as_float(x), __int_as_float(t)));
    t = __builtin_amdgcn_update_dpp(x, x, 0x142, 0xa, 0xf, false);  // row_bcast:15
    x = __float_as_int(fmaxf(__int_as_float(x), __int_as_float(t)));
    t = __builtin_amdgcn_update_dpp(x, x, 0x143, 0xc, 0xf, false);  // row_bcast:31
    x = __float_as_int(fmaxf(__int_as_float(x), __int_as_float(t)));
    return __int_as_float(__builtin_amdgcn_readlane(x, 63));
}

__device__ __forceinline__ unsigned wave_min_bcast_u32(unsigned v) {
    int x = (int)v;
    int t;
    t = __builtin_amdgcn_update_dpp(x, x, 0x111, 0xf, 0xf, false);
    x = (int)min((unsigned)x, (unsigned)t);
    t = __builtin_amdgcn_update_dpp(x, x, 0x112, 0xf, 0xf, false);
    x = (int)min((unsigned)x, (unsigned)t);
    t = __builtin_amdgcn_update_dpp(x, x, 0x114, 0xf, 0xf, false);
    x = (int)min((unsigned)x, (unsigned)t);
    t = __builtin_amdgcn_update_dpp(x, x, 0x118, 0xf, 0xf, false);
    x = (int)min((unsigned)x, (unsigned)t);
    t = __builtin_amdgcn_update_dpp(x, x, 0x142, 0xa, 0xf, false);
    x = (int)min((unsigned)x, (unsigned)t);
    t = __builtin_amdgcn_update_dpp(x, x, 0x143, 0xc, 0xf, false);
    x = (int)min((unsigned)x, (unsigned)t);
    return (unsigned)__builtin_amdgcn_readlane(x, 63);
}

// ---------------------------------------------------------------------------
// OMP core for one column (shared by split and fused paths).
// h[] preloaded by caller; writes gamma/recon/zf-err/entropy contributions.
__device__ __forceinline__ void omp_column(float h[8], const int n, const int lane,
                                           const float* __restrict__ G,
                                           const float* __restrict__ DnT,
                                           float* __restrict__ out,
                                           float xd, float& wv_sq, float& wv_S) {
    unsigned msk = 0;
    float uv[56], Lr[28], invd[8], yv[8], xr[8];
    int Iv[8];

    #pragma unroll
    for (int k = 0; k < 8; ++k) {
        // local argmax over this lane's 8 slots (track signed winner)
        float bv = -1.f; int bi = 0; float hb = 0.f;
        #pragma unroll
        for (int r = 0; r < 8; ++r) {
            float av = ((msk >> r) & 1) ? -1.f : fabsf(h[r]);
            bool gt = av > bv;
            bv = gt ? av : bv;
            bi = gt ? ((r << 6) | lane) : bi;
            hb = gt ? h[r] : hb;
        }
        float maxv = wave_max_bcast_f32(bv);
        unsigned cand = (bv == maxv) ? (unsigned)bi : 0xffffffffu;
        const int idx = (int)wave_min_bcast_u32(cand);
        unsigned long long sm = __ballot((bv == maxv) && (bi == idx) && (hb < 0.f));
        float hwin = (sm != 0ull) ? -maxv : maxv;

        if ((idx & 63) == lane) msk |= 1u << (idx >> 6);
        Iv[k] = idx;

        const float* grow = G + idx * KAT;
        float gk[8];
        if (k < 7) {
            #pragma unroll
            for (int r = 0; r < 8; ++r) gk[r] = grow[(r << 6) + lane];
        }

        // replicated Cholesky rank-1 extension (uniform loads, short FMA chains)
        float Lk[7];
        if (k == 0) {
            invd[0] = 1.f;
        } else {
            float s2 = 0.f;
            #pragma unroll
            for (int i = 0; i < 7; ++i) if (i < k) {
                float a = grow[Iv[i]];              // == G[Iv[i]][idx]
                #pragma unroll
                for (int j = 0; j < 7; ++j) if (j < i)
                    a = fmaf(-Lr[i*(i-1)/2 + j], Lk[j], a);
                Lk[i] = a * invd[i];
                s2 = fmaf(Lk[i], Lk[i], s2);
            }
            #pragma unroll
            for (int j = 0; j < 7; ++j) if (j < k) Lr[k*(k-1)/2 + j] = Lk[j];
            invd[k] = 1.f / sqrtf(1.f - s2);
        }
        yv[k] = hwin * invd[k];

        if (k < 7) {
            #pragma unroll
            for (int r = 0; r < 8; ++r) {
                float a = gk[r];
                #pragma unroll
                for (int j = 0; j < 7; ++j) if (j < k)
                    a = fmaf(-Lk[j], uv[j*8 + r], a);
                a *= invd[k];
                uv[k*8 + r] = a;
                h[r] = fmaf(-yv[k], a, h[r]);
            }
        }
    }

    // single back solve: L^T xr = yv
    #pragma unroll
    for (int i = 7; i >= 0; --i) {
        float a = yv[i];
        #pragma unroll
        for (int j = 0; j < 8; ++j) if (j > i)
            a = fmaf(-Lr[j*(j-1)/2 + i], xr[j], a);
        xr[i] = a * invd[i];
    }

    // gamma scatter
    #pragma unroll
    for (int j = 0; j < 8; ++j)
        if (lane == j) out[O_GAMMA + Iv[j] * NCOL + n] = xr[j];

    // recon (lane = d), through the output permutation
    float rec = 0.f;
    #pragma unroll
    for (int j = 0; j < 8; ++j)
        rec = fmaf(xr[j], DnT[Iv[j] * DIM + lane], rec);
    int Lf = lane * NCOL + n;
    int perm = (Lf >> 16) * 65536 + (Lf & 63) * 1024 + (((Lf >> 11) & 31) << 5) + ((Lf >> 6) & 31);
    out[O_RECON + perm] = rec;

    // squared-error partial
    float diff = rec - xd;
    float sq = diff * diff;
    #pragma unroll
    for (int off = 32; off; off >>= 1) sq += __shfl_xor(sq, off, 64);
    if (lane == 0) wv_sq += sq;

    // softmax-entropy: 8 nnz + 504 zeros, parallel over lanes 0..7
    {
        float m = 0.f;
        #pragma unroll
        for (int j = 0; j < 8; ++j) m = fmaxf(m, xr[j]);
        float xsel = 0.f;
        #pragma unroll
        for (int j = 0; j < 8; ++j) xsel = (lane == j) ? xr[j] : xsel;
        float e = (lane < 8) ? expf(xsel - m) : 0.f;
        float se = e;
        #pragma unroll
        for (int off = 1; off < 8; off <<= 1) se += __shfl_xor(se, off, 64);
        float e0 = expf(-m);
        float Z = fmaf(504.f, e0, se);       // valid on lanes 0..7
        float invZ = 1.f / Z;
        float p = e * invZ;
        float tq = (lane < 8) ? p * logf(p + 1e-10f) : 0.f;
        #pragma unroll
        for (int off = 1; off < 8; off <<= 1) tq += __shfl_xor(tq, off, 64);
        if (lane == 0) {
            float p0 = e0 * invZ;
            wv_S += tq + 504.f * p0 * logf(p0 + 1e-10f);
        }
    }
}

// ---------------------------------------------------------------------------
// Kernel 1: gamma zero-fill (all 8192 blocks) + block 0: dict normalize + acc init.
__global__ __launch_bounds__(256) void init_kernel(const float* __restrict__ dict,
                                                   float* __restrict__ ws,
                                                   float* __restrict__ out) {
    int id = blockIdx.x * 256 + threadIdx.x;
    float2* g2 = (float2*)(out + O_GAMMA);      // 8B-aligned region
    #pragma unroll
    for (int i = 0; i < 4; ++i)
        g2[id + i * 2097152] = make_float2(0.f, 0.f);

    if (blockIdx.x == 0) {
        float* Dn  = ws + WS_DN;
        float* DnT = ws + WS_DNT;
        float* acc = ws + WS_ACC;
        int t = threadIdx.x;
        if (t == 0) { acc[0] = 0.f; acc[1] = 0.f; ((unsigned*)acc)[2] = 0u; }
        #pragma unroll
        for (int half = 0; half < 2; ++half) {
            int a = t + half * 256;
            float s = 0.f;
            #pragma unroll
            for (int d = 0; d < DIM; ++d) { float v = dict[d*KAT + a]; s += v * v; }
            float nrm = sqrtf(s);
            #pragma unroll
            for (int d = 0; d < DIM; ++d) {
                float v = dict[d*KAT + a] / nrm;
                Dn[d*KAT + a]  = v;
                DnT[a*DIM + d] = v;
            }
        }
    }
}

// ---------------------------------------------------------------------------
// Kernel 2: G = Dn^T Dn.
__global__ void gram_kernel(const float* __restrict__ ws_in, float* __restrict__ ws) {
    const float* Dn = ws_in + WS_DN;
    float* G = ws + WS_G;
    int i = blockIdx.x, j = threadIdx.x;
    float s = 0.f;
    #pragma unroll
    for (int d = 0; d < DIM; ++d)
        s = fmaf(Dn[d*KAT + i], Dn[d*KAT + j], s);
    G[i*KAT + j] = s;
}

// ---------------------------------------------------------------------------
// Kernel 3a (split path): gather + zf echo + h_bar GEMM -> global hbar & xT.
__global__ __launch_bounds__(256) void hb_kernel(const float* __restrict__ z_e,
                                                 const float* __restrict__ ws,
                                                 float* __restrict__ wsw,
                                                 float* __restrict__ out) {
    const float* Dn = ws + WS_DN;
    float* xT  = wsw + WS_XT;
    float* hbg = wsw + WS_HB;

    __shared__ float xcols[DIM * 16];     // [d][c]  4 KB
    __shared__ float xclT[16 * 65];       // [c][d]  pad 65, conflict-free

    const int t = threadIdx.x;
    const int n_base = blockIdx.x * 16;

    // gather + zf echo
    #pragma unroll
    for (int i = 0; i < 4; ++i) {
        int e = t + i * 256;              // 0..1023
        int d = e >> 4, c = e & 15;
        int Lf = d * NCOL + n_base + c;
        int src = (Lf >> 16) * 65536 + (Lf & 63) * 1024 + (((Lf >> 11) & 31) << 5) + ((Lf >> 6) & 31);
        float v = z_e[src];
        xcols[e] = v;
        xclT[c * 65 + d] = v;
        out[O_ZF + Lf] = v;
    }
    __syncthreads();

    // xT store (coalesced from padded LDS)
    #pragma unroll
    for (int i = 0; i < 4; ++i) {
        int e = t + i * 256;              // e = c*64 + d
        int c = e >> 6, d = e & 63;
        xT[(n_base + c) * DIM + d] = xclT[c * 65 + d];
    }

    // h_bar GEMM (Dn read once per block), stream to global
    float a0[16], a1[16];
    #pragma unroll
    for (int i = 0; i < 16; ++i) { a0[i] = 0.f; a1[i] = 0.f; }
    const float4* xc4 = (const float4*)xcols;
    for (int d = 0; d < DIM; ++d) {
        float v0 = Dn[d * KAT + t];
        float v1 = Dn[d * KAT + 256 + t];
        #pragma unroll
        for (int q = 0; q < 4; ++q) {
            float4 xv = xc4[d * 4 + q];
            a0[q*4+0] = fmaf(v0, xv.x, a0[q*4+0]);
            a0[q*4+1] = fmaf(v0, xv.y, a0[q*4+1]);
            a0[q*4+2] = fmaf(v0, xv.z, a0[q*4+2]);
            a0[q*4+3] = fmaf(v0, xv.w, a0[q*4+3]);
            a1[q*4+0] = fmaf(v1, xv.x, a1[q*4+0]);
            a1[q*4+1] = fmaf(v1, xv.y, a1[q*4+1]);
            a1[q*4+2] = fmaf(v1, xv.z, a1[q*4+2]);
            a1[q*4+3] = fmaf(v1, xv.w, a1[q*4+3]);
        }
    }
    #pragma unroll
    for (int c = 0; c < 16; ++c) {
        hbg[(n_base + c) * KAT + t]       = a0[c];
        hbg[(n_base + c) * KAT + 256 + t] = a1[c];
    }
}

// ---------------------------------------------------------------------------
// Kernel 4a (split path): LDS-free OMP, 1 column per wave + last-block finalize.
__global__ __launch_bounds__(256) void omp_kernel(const float* __restrict__ ws,
                                                  const float* __restrict__ wsr,
                                                  float* __restrict__ out,
                                                  const float* __restrict__ beta,
                                                  float* __restrict__ wsw) {
    const float* DnT = ws + WS_DNT;
    const float* G   = ws + WS_G;
    const float* xT  = wsr + WS_XT;
    const float* hbg = wsr + WS_HB;
    float* acc = wsw + WS_ACC;

    __shared__ float red[8];

    const int t = threadIdx.x;
    const int wv = t >> 6, lane = t & 63;
    const int n = blockIdx.x * 4 + wv;

    float h[8];
    const float* hb = hbg + n * KAT;
    #pragma unroll
    for (int r = 0; r < 8; ++r) h[r] = hb[(r << 6) + lane];
    float xd = xT[n * DIM + lane];

    float wv_sq = 0.f, wv_S = 0.f;
    omp_column(h, n, lane, G, DnT, out, xd, wv_sq, wv_S);

    if (lane == 0) { red[wv] = wv_sq; red[4 + wv] = wv_S; }
    __syncthreads();
    if (t == 0) {
        atomicAdd(&acc[0], red[0] + red[1] + red[2] + red[3]);
        atomicAdd(&acc[1], red[4] + red[5] + red[6] + red[7]);
        __threadfence();
        unsigned old = atomicAdd((unsigned*)acc + 2, 1u);
        if (old == gridDim.x - 1) {
            __threadfence();
            float s0 = atomicAdd(&acc[0], 0.f);
            float s1 = atomicAdd(&acc[1], 0.f);
            float mse = s0 / 2097152.f;
            out[O_LOSS] = mse * 0.25f + beta[0] * mse;
            out[O_PERP] = expf(-s1 / 32768.f);
        }
    }
}

// ---------------------------------------------------------------------------
// Kernel 3b/4b (fallback, small ws): round-5 fused kernel (LDS h_bar).
__global__ __launch_bounds__(256) void omp_fused_kernel(const float* __restrict__ z_e,
                                                        const float* __restrict__ ws,
                                                        float* __restrict__ out,
                                                        const float* __restrict__ beta,
                                                        float* __restrict__ wsw) {
    const float* Dn  = ws + WS_DN;
    const float* DnT = ws + WS_DNT;
    const float* G   = ws + WS_G;
    float* acc = wsw + WS_ACC;

    __shared__ float xcols[DIM * 16];
    __shared__ float hbar[16 * KAT];

    const int t = threadIdx.x;
    const int n_base = blockIdx.x * 16;

    #pragma unroll
    for (int i = 0; i < 4; ++i) {
        int e = t + i * 256;
        int d = e >> 4, c = e & 15;
        int Lf = d * NCOL + n_base + c;
        int src = (Lf >> 16) * 65536 + (Lf & 63) * 1024 + (((Lf >> 11) & 31) << 5) + ((Lf >> 6) & 31);
        float v = z_e[src];
        xcols[e] = v;
        out[O_ZF + Lf] = v;
    }
    __syncthreads();

    {
        float a0[16], a1[16];
        #pragma unroll
        for (int i = 0; i < 16; ++i) { a0[i] = 0.f; a1[i] = 0.f; }
        const float4* xc4 = (const float4*)xcols;
        for (int d = 0; d < DIM; ++d) {
            float v0 = Dn[d * KAT + t];
            float v1 = Dn[d * KAT + 256 + t];
            #pragma unroll
            for (int q = 0; q < 4; ++q) {
                float4 xv = xc4[d * 4 + q];
                a0[q*4+0] = fmaf(v0, xv.x, a0[q*4+0]);
                a0[q*4+1] = fmaf(v0, xv.y, a0[q*4+1]);
                a0[q*4+2] = fmaf(v0, xv.z, a0[q*4+2]);
                a0[q*4+3] = fmaf(v0, xv.w, a0[q*4+3]);
                a1[q*4+0] = fmaf(v1, xv.x, a1[q*4+0]);
                a1[q*4+1] = fmaf(v1, xv.y, a1[q*4+1]);
                a1[q*4+2] = fmaf(v1, xv.z, a1[q*4+2]);
                a1[q*4+3] = fmaf(v1, xv.w, a1[q*4+3]);
            }
        }
        #pragma unroll
        for (int c = 0; c < 16; ++c) {
            hbar[c * KAT + t]       = a0[c];
            hbar[c * KAT + 256 + t] = a1[c];
        }
    }
    __syncthreads();

    const int wv = t >> 6, lane = t & 63;
    float wv_sq = 0.f, wv_S = 0.f;

    #pragma unroll 1
    for (int cc = 0; cc < 4; ++cc) {
        const int col = wv * 4 + cc;
        const int n = n_base + col;
        float h[8];
        #pragma unroll
        for (int r = 0; r < 8; ++r) h[r] = hbar[col * KAT + (r << 6) + lane];
        float xd = xcols[lane * 16 + col];
        omp_column(h, n, lane, G, DnT, out, xd, wv_sq, wv_S);
    }

    if (lane == 0) {
        atomicAdd(&acc[0], wv_sq);
        atomicAdd(&acc[1], wv_S);
    }
    __threadfence();
    __syncthreads();
    if (t == 0) {
        unsigned old = atomicAdd((unsigned*)acc + 2, 1u);
        if (old == gridDim.x - 1) {
            __threadfence();
            float s0 = atomicAdd(&acc[0], 0.f);
            float s1 = atomicAdd(&acc[1], 0.f);
            float mse = s0 / 2097152.f;
            out[O_LOSS] = mse * 0.25f + beta[0] * mse;
            out[O_PERP] = expf(-s1 / 32768.f);
        }
    }
}

// ---------------------------------------------------------------------------
extern "C" void kernel_launch(void* const* d_in, const int* in_sizes, int n_in,
                              void* d_out, int out_size, void* d_ws, size_t ws_size,
                              hipStream_t stream) {
    const float* z_e  = (const float*)d_in[0];
    const float* dict = (const float*)d_in[1];
    const float* beta = (const float*)d_in[2];
    float* out = (float*)d_out;
    float* ws  = (float*)d_ws;

    init_kernel<<<8192, 256, 0, stream>>>(dict, ws, out);
    gram_kernel<<<512, 512, 0, stream>>>(ws, ws);
    if (ws_size >= WS_NEED) {
        hb_kernel<<<2048, 256, 0, stream>>>(z_e, ws, ws, out);
        omp_kernel<<<8192, 256, 0, stream>>>(ws, ws, out, beta, ws);
    } else {
        omp_fused_kernel<<<2048, 256, 0, stream>>>(z_e, ws, out, beta, ws);
    }
}

// Round 8
// 519.233 us; speedup vs baseline: 1.0441x; 1.0043x over previous
//
#include <hip/hip_runtime.h>
#include <math.h>

// Problem constants
#define NCOL 32768          // N = 32*32*32 columns
#define KAT  512            // dictionary atoms
#define DIM  64             // embedding dim

// Output flat offsets (fp32 elements)
#define O_LOSS  0
#define O_RECON 1
#define O_ZF    2097153     // 1 + 2097152
#define O_PERP  4194305
#define O_GAMMA 4194306

// Workspace layout (fp32 elements)
#define WS_DN   0           // Dn  [64][512]
#define WS_DNT  32768       // DnT [512][64]
#define WS_G    65536       // G   [512][512]
#define WS_ACC  327680      // acc[0]=sum sq, acc[1]=sum S, acc[2]=block counter

// ---------------------------------------------------------------------------
// DPP wave-64 reductions (all-VALU; result broadcast via readlane)
__device__ __forceinline__ float wave_max_bcast_f32(float v) {
    int x = __float_as_int(v);
    int t;
    t = __builtin_amdgcn_update_dpp(x, x, 0x111, 0xf, 0xf, false);  // row_shr:1
    x = __float_as_int(fmaxf(__int_as_float(x), __int_as_float(t)));
    t = __builtin_amdgcn_update_dpp(x, x, 0x112, 0xf, 0xf, false);  // row_shr:2
    x = __float_as_int(fmaxf(__int_as_float(x), __int_as_float(t)));
    t = __builtin_amdgcn_update_dpp(x, x, 0x114, 0xf, 0xf, false);  // row_shr:4
    x = __float_as_int(fmaxf(__int_as_float(x), __int_as_float(t)));
    t = __builtin_amdgcn_update_dpp(x, x, 0x118, 0xf, 0xf, false);  // row_shr:8
    x = __float_as_int(fmaxf(__int_as_float(x), __int_as_float(t)));
    t = __builtin_amdgcn_update_dpp(x, x, 0x142, 0xa, 0xf, false);  // row_bcast:15
    x = __float_as_int(fmaxf(__int_as_float(x), __int_as_float(t)));
    t = __builtin_amdgcn_update_dpp(x, x, 0x143, 0xc, 0xf, false);  // row_bcast:31
    x = __float_as_int(fmaxf(__int_as_float(x), __int_as_float(t)));
    return __int_as_float(__builtin_amdgcn_readlane(x, 63));
}

__device__ __forceinline__ unsigned wave_min_bcast_u32(unsigned v) {
    int x = (int)v;
    int t;
    t = __builtin_amdgcn_update_dpp(x, x, 0x111, 0xf, 0xf, false);
    x = (int)min((unsigned)x, (unsigned)t);
    t = __builtin_amdgcn_update_dpp(x, x, 0x112, 0xf, 0xf, false);
    x = (int)min((unsigned)x, (unsigned)t);
    t = __builtin_amdgcn_update_dpp(x, x, 0x114, 0xf, 0xf, false);
    x = (int)min((unsigned)x, (unsigned)t);
    t = __builtin_amdgcn_update_dpp(x, x, 0x118, 0xf, 0xf, false);
    x = (int)min((unsigned)x, (unsigned)t);
    t = __builtin_amdgcn_update_dpp(x, x, 0x142, 0xa, 0xf, false);
    x = (int)min((unsigned)x, (unsigned)t);
    t = __builtin_amdgcn_update_dpp(x, x, 0x143, 0xc, 0xf, false);
    x = (int)min((unsigned)x, (unsigned)t);
    return (unsigned)__builtin_amdgcn_readlane(x, 63);
}

// full-wave sum, total at lane 63 -> broadcast
__device__ __forceinline__ float wave_sum_f32(float v) {
    float x = v;
    int t;
    t = __builtin_amdgcn_update_dpp(0, __float_as_int(x), 0x111, 0xf, 0xf, true);
    x += __int_as_float(t);
    t = __builtin_amdgcn_update_dpp(0, __float_as_int(x), 0x112, 0xf, 0xf, true);
    x += __int_as_float(t);
    t = __builtin_amdgcn_update_dpp(0, __float_as_int(x), 0x114, 0xf, 0xf, true);
    x += __int_as_float(t);
    t = __builtin_amdgcn_update_dpp(0, __float_as_int(x), 0x118, 0xf, 0xf, true);
    x += __int_as_float(t);
    t = __builtin_amdgcn_update_dpp(0, __float_as_int(x), 0x142, 0xa, 0xf, false);
    x += __int_as_float(t);
    t = __builtin_amdgcn_update_dpp(0, __float_as_int(x), 0x143, 0xc, 0xf, false);
    x += __int_as_float(t);
    return __int_as_float(__builtin_amdgcn_readlane(__float_as_int(x), 63));
}

// sum over each 8-lane group (quad_perm xor1, xor2, half_mirror)
__device__ __forceinline__ float sum8_f32(float v) {
    float x = v;
    int t;
    t = __builtin_amdgcn_update_dpp(0, __float_as_int(x), 0xB1, 0xf, 0xf, false);
    x += __int_as_float(t);
    t = __builtin_amdgcn_update_dpp(0, __float_as_int(x), 0x4E, 0xf, 0xf, false);
    x += __int_as_float(t);
    t = __builtin_amdgcn_update_dpp(0, __float_as_int(x), 0x141, 0xf, 0xf, false);
    x += __int_as_float(t);
    return x;
}

// ---------------------------------------------------------------------------
// Kernel 1: float4 zero-fill of [O_PERP..gamma end) + block 0: prep Dn/DnT/acc.
__global__ __launch_bounds__(256) void init_kernel(const float* __restrict__ dict,
                                                   float* __restrict__ ws,
                                                   float* __restrict__ out) {
    int id = blockIdx.x * 256 + threadIdx.x;       // 4096 blocks -> 1048576 ids
    float4* g4 = (float4*)(out + 4194304);         // 16B-aligned; covers O_PERP+gamma
    float4 z = make_float4(0.f, 0.f, 0.f, 0.f);
    #pragma unroll
    for (int i = 0; i < 4; ++i)
        g4[id + i * 1048576] = z;                  // elems 4194304..20971519

    if (blockIdx.x == 0) {
        int t = threadIdx.x;
        if (t == 0) {                              // gamma tail
            out[20971520] = 0.f; out[20971521] = 0.f;
        }
        float* Dn  = ws + WS_DN;
        float* DnT = ws + WS_DNT;
        float* acc = ws + WS_ACC;
        if (t == 0) { acc[0] = 0.f; acc[1] = 0.f; ((unsigned*)acc)[2] = 0u; }
        #pragma unroll
        for (int half = 0; half < 2; ++half) {
            int a = t + half * 256;
            float s = 0.f;
            #pragma unroll
            for (int d = 0; d < DIM; ++d) { float v = dict[d*KAT + a]; s += v * v; }
            float nrm = sqrtf(s);
            #pragma unroll
            for (int d = 0; d < DIM; ++d) {
                float v = dict[d*KAT + a] / nrm;
                Dn[d*KAT + a]  = v;
                DnT[a*DIM + d] = v;
            }
        }
    }
}

// ---------------------------------------------------------------------------
// Kernel 2: G = Dn^T Dn.
__global__ void gram_kernel(const float* __restrict__ ws_in, float* __restrict__ ws) {
    const float* Dn = ws_in + WS_DN;
    float* G = ws + WS_G;
    int i = blockIdx.x, j = threadIdx.x;
    float s = 0.f;
    #pragma unroll
    for (int d = 0; d < DIM; ++d)
        s = fmaf(Dn[d*KAT + i], Dn[d*KAT + j], s);
    G[i*KAT + j] = s;
}

// ---------------------------------------------------------------------------
// Kernel 3: fused zf-echo + h_bar + Batch-OMP + coalesced recon + finalize.
// 16 columns per 256-thread block, one wave per column, 4 columns/wave.
__global__ __launch_bounds__(256) void omp_kernel(const float* __restrict__ z_e,
                                                  const float* __restrict__ ws,
                                                  float* __restrict__ out,
                                                  const float* __restrict__ beta,
                                                  float* __restrict__ wsw) {
    const float* Dn  = ws + WS_DN;
    const float* DnT = ws + WS_DNT;
    const float* G   = ws + WS_G;
    float* acc = wsw + WS_ACC;

    __shared__ float xcols[DIM * 16];     // [d][c]   4 KB
    __shared__ float hbar[16 * KAT];      // [c][a]  32 KB
    __shared__ float lds_rec[DIM * 16];   // [d][c]   4 KB (XOR-swizzled)

    const int t = threadIdx.x;
    const int n_base = blockIdx.x * 16;

    // ---- Phase 1: gather data columns; echo to zf output region
    #pragma unroll
    for (int i = 0; i < 4; ++i) {
        int e = t + i * 256;              // 0..1023
        int d = e >> 4, c = e & 15;
        int Lf = d * NCOL + n_base + c;
        int src = (Lf >> 16) * 65536 + (Lf & 63) * 1024 + (((Lf >> 11) & 31) << 5) + ((Lf >> 6) & 31);
        float v = z_e[src];
        xcols[e] = v;
        out[O_ZF + Lf] = v;
    }
    __syncthreads();

    // ---- Phase 2: h_bar tile (Dn read once per block)
    {
        float a0[16], a1[16];
        #pragma unroll
        for (int i = 0; i < 16; ++i) { a0[i] = 0.f; a1[i] = 0.f; }
        const float4* xc4 = (const float4*)xcols;
        for (int d = 0; d < DIM; ++d) {
            float v0 = Dn[d * KAT + t];
            float v1 = Dn[d * KAT + 256 + t];
            #pragma unroll
            for (int q = 0; q < 4; ++q) {
                float4 xv = xc4[d * 4 + q];
                a0[q*4+0] = fmaf(v0, xv.x, a0[q*4+0]);
                a0[q*4+1] = fmaf(v0, xv.y, a0[q*4+1]);
                a0[q*4+2] = fmaf(v0, xv.z, a0[q*4+2]);
                a0[q*4+3] = fmaf(v0, xv.w, a0[q*4+3]);
                a1[q*4+0] = fmaf(v1, xv.x, a1[q*4+0]);
                a1[q*4+1] = fmaf(v1, xv.y, a1[q*4+1]);
                a1[q*4+2] = fmaf(v1, xv.z, a1[q*4+2]);
                a1[q*4+3] = fmaf(v1, xv.w, a1[q*4+3]);
            }
        }
        #pragma unroll
        for (int c = 0; c < 16; ++c) {
            hbar[c * KAT + t]       = a0[c];
            hbar[c * KAT + 256 + t] = a1[c];
        }
    }
    __syncthreads();

    // ---- Phase 3: OMP, one wave per column, 4 columns sequentially
    const int wv = t >> 6, lane = t & 63;
    float wv_sq = 0.f, wv_S = 0.f;

    #pragma unroll 1
    for (int cc = 0; cc < 4; ++cc) {
        const int col = wv * 4 + cc;
        const int n = n_base + col;
        const float* hbcol = hbar + col * KAT;

        float h[8];
        #pragma unroll
        for (int r = 0; r < 8; ++r) h[r] = hbcol[(r << 6) + lane];

        unsigned msk = 0;
        float uv[56];                 // u_0..u_6, uv[j*8+r]
        float Lr[28];                 // off-diag rows 1..7: Lr[i*(i-1)/2+j], j<i
        float invd[8], yv[8], xr[8];
        int Iv[8];

        #pragma unroll
        for (int k = 0; k < 8; ++k) {
            // local argmax over this lane's 8 slots (track signed winner)
            float bv = -1.f; int bi = 0; float hb = 0.f;
            #pragma unroll
            for (int r = 0; r < 8; ++r) {
                float av = ((msk >> r) & 1) ? -1.f : fabsf(h[r]);
                bool gt = av > bv;
                bv = gt ? av : bv;
                bi = gt ? ((r << 6) | lane) : bi;
                hb = gt ? h[r] : hb;
            }
            // wave max, then first-index among exact ties via u32 min
            float maxv = wave_max_bcast_f32(bv);
            unsigned cand = (bv == maxv) ? (unsigned)bi : 0xffffffffu;
            const int idx = __builtin_amdgcn_readfirstlane(
                                (int)wave_min_bcast_u32(cand));   // SGPR
            // signed winner h[idx] = +-maxv via one ballot
            unsigned long long sm = __ballot((bv == maxv) && (bi == idx) && (hb < 0.f));
            float hwin = (sm != 0ull) ? -maxv : maxv;

            if ((idx & 63) == lane) msk |= 1u << (idx >> 6);
            Iv[k] = idx;

            const float* grow = G + idx * KAT;   // scalar base -> s_load/saddr
            float gk[8];
            if (k < 7) {
                #pragma unroll
                for (int r = 0; r < 8; ++r) gk[r] = grow[(r << 6) + lane];
            }

            // replicated Cholesky rank-1 extension (uniform scalar loads)
            float Lk[7];
            if (k == 0) {
                invd[0] = 1.f;
            } else {
                float s2 = 0.f;
                #pragma unroll
                for (int i = 0; i < 7; ++i) if (i < k) {
                    float a = grow[Iv[i]];              // == G[Iv[i]][idx]
                    #pragma unroll
                    for (int j = 0; j < 7; ++j) if (j < i)
                        a = fmaf(-Lr[i*(i-1)/2 + j], Lk[j], a);
                    Lk[i] = a * invd[i];
                    s2 = fmaf(Lk[i], Lk[i], s2);
                }
                #pragma unroll
                for (int j = 0; j < 7; ++j) if (j < k) Lr[k*(k-1)/2 + j] = Lk[j];
                invd[k] = 1.f / sqrtf(1.f - s2);
            }
            yv[k] = hwin * invd[k];

            // u_k and incremental h update (not needed after last pick)
            if (k < 7) {
                #pragma unroll
                for (int r = 0; r < 8; ++r) {
                    float a = gk[r];
                    #pragma unroll
                    for (int j = 0; j < 7; ++j) if (j < k)
                        a = fmaf(-Lk[j], uv[j*8 + r], a);
                    a *= invd[k];
                    uv[k*8 + r] = a;
                    h[r] = fmaf(-yv[k], a, h[r]);
                }
            }
        }

        // single back solve: L^T xr = yv  (xr is lane-uniform)
        #pragma unroll
        for (int i = 7; i >= 0; --i) {
            float a = yv[i];
            #pragma unroll
            for (int j = 0; j < 8; ++j) if (j > i)
                a = fmaf(-Lr[j*(j-1)/2 + i], xr[j], a);
            xr[i] = a * invd[i];
        }

        // gamma scatter: one 8-lane store (xr/Iv uniform across lanes)
        {
            float gv = xr[0]; int ai = Iv[0];
            #pragma unroll
            for (int j = 1; j < 8; ++j) {
                bool m = (lane == j);
                gv = m ? xr[j] : gv;
                ai = m ? Iv[j] : ai;
            }
            if (lane < 8) out[O_GAMMA + ai * NCOL + n] = gv;
        }

        // recon (lane = d): stash in swizzled LDS for coalesced write later
        float rec = 0.f;
        #pragma unroll
        for (int j = 0; j < 8; ++j)
            rec = fmaf(xr[j], DnT[Iv[j] * DIM + lane], rec);
        lds_rec[lane * 16 + (col ^ (lane & 15))] = rec;

        // squared-error partial (DPP sum)
        float xd = xcols[lane * 16 + col];
        float diff = rec - xd;
        float sq = wave_sum_f32(diff * diff);
        if (lane == 0) wv_sq += sq;

        // softmax-entropy: 8 nnz + 504 zeros, parallel over lanes 0..7
        {
            float m = 0.f;
            #pragma unroll
            for (int j = 0; j < 8; ++j) m = fmaxf(m, xr[j]);
            float xsel = 0.f;
            #pragma unroll
            for (int j = 0; j < 8; ++j) xsel = (lane == j) ? xr[j] : xsel;
            float e = (lane < 8) ? __expf(xsel - m) : 0.f;
            float se = sum8_f32(e);
            float e0 = __expf(-m);
            float Z = fmaf(504.f, e0, se);       // valid on lanes 0..7
            float invZ = 1.f / Z;
            float p = e * invZ;
            float tq = (lane < 8) ? p * __logf(p + 1e-10f) : 0.f;
            tq = sum8_f32(tq);
            if (lane == 0) {
                float p0 = e0 * invZ;
                wv_S += tq + 504.f * p0 * __logf(p0 + 1e-10f);
            }
        }
    }

    // ---- coalesced recon write-out (16 consecutive floats per 16-lane group)
    __syncthreads();
    #pragma unroll
    for (int i = 0; i < 4; ++i) {
        int e = t + i * 256;              // 0..1023
        int d = e >> 4, c = e & 15;
        float rec = lds_rec[d * 16 + (c ^ (d & 15))];
        int Lf = d * NCOL + n_base + c;
        int perm = (Lf >> 16) * 65536 + (Lf & 63) * 1024 + (((Lf >> 11) & 31) << 5) + ((Lf >> 6) & 31);
        out[O_RECON + perm] = rec;
    }

    if (lane == 0) {
        atomicAdd(&acc[0], wv_sq);
        atomicAdd(&acc[1], wv_S);
    }
    __threadfence();            // release: acc adds visible before counter bump
    __syncthreads();
    if (t == 0) {
        unsigned old = atomicAdd((unsigned*)acc + 2, 1u);
        if (old == gridDim.x - 1) {                 // last block finalizes
            __threadfence();                        // acquire
            float s0 = atomicAdd(&acc[0], 0.f);     // coherent L2 reads
            float s1 = atomicAdd(&acc[1], 0.f);
            float mse = s0 / 2097152.f;
            out[O_LOSS] = mse * 0.25f + beta[0] * mse;
            out[O_PERP] = __expf(-s1 / 32768.f);
        }
    }
}

// ---------------------------------------------------------------------------
extern "C" void kernel_launch(void* const* d_in, const int* in_sizes, int n_in,
                              void* d_out, int out_size, void* d_ws, size_t ws_size,
                              hipStream_t stream) {
    const float* z_e  = (const float*)d_in[0];
    const float* dict = (const float*)d_in[1];
    const float* beta = (const float*)d_in[2];
    float* out = (float*)d_out;
    float* ws  = (float*)d_ws;

    init_kernel<<<4096, 256, 0, stream>>>(dict, ws, out);
    gram_kernel<<<512, 512, 0, stream>>>(ws, ws);
    omp_kernel<<<2048, 256, 0, stream>>>(z_e, ws, out, beta, ws);
}

// Round 9
// 451.586 us; speedup vs baseline: 1.2005x; 1.1498x over previous
//
#include <hip/hip_runtime.h>
#include <math.h>

// Problem constants
#define NCOL 32768          // N = 32*32*32 columns
#define KAT  512            // dictionary atoms
#define DIM  64             // embedding dim

// Output flat offsets (fp32 elements)
#define O_LOSS  0
#define O_RECON 1
#define O_ZF    2097153     // 1 + 2097152
#define O_PERP  4194305
#define O_GAMMA 4194306

// Workspace layout (fp32 elements)
#define WS_DN   0           // Dn  [64][512]
#define WS_DNT  32768       // DnT [512][64]
#define WS_G    65536       // G   [512][512]
#define WS_ACC  327680      // acc[0]=sum sq, acc[1]=sum S, acc[2]=block counter
#define WS_REC  327696      // rec [32768][64]  (8 MB, coalesced staging)

// ---------------------------------------------------------------------------
// DPP wave-64 reductions (all-VALU; result broadcast via readlane)
__device__ __forceinline__ float wave_max_bcast_f32(float v) {
    int x = __float_as_int(v);
    int t;
    t = __builtin_amdgcn_update_dpp(x, x, 0x111, 0xf, 0xf, false);  // row_shr:1
    x = __float_as_int(fmaxf(__int_as_float(x), __int_as_float(t)));
    t = __builtin_amdgcn_update_dpp(x, x, 0x112, 0xf, 0xf, false);  // row_shr:2
    x = __float_as_int(fmaxf(__int_as_float(x), __int_as_float(t)));
    t = __builtin_amdgcn_update_dpp(x, x, 0x114, 0xf, 0xf, false);  // row_shr:4
    x = __float_as_int(fmaxf(__int_as_float(x), __int_as_float(t)));
    t = __builtin_amdgcn_update_dpp(x, x, 0x118, 0xf, 0xf, false);  // row_shr:8
    x = __float_as_int(fmaxf(__int_as_float(x), __int_as_float(t)));
    t = __builtin_amdgcn_update_dpp(x, x, 0x142, 0xa, 0xf, false);  // row_bcast:15
    x = __float_as_int(fmaxf(__int_as_float(x), __int_as_float(t)));
    t = __builtin_amdgcn_update_dpp(x, x, 0x143, 0xc, 0xf, false);  // row_bcast:31
    x = __float_as_int(fmaxf(__int_as_float(x), __int_as_float(t)));
    return __int_as_float(__builtin_amdgcn_readlane(x, 63));
}

__device__ __forceinline__ unsigned wave_min_bcast_u32(unsigned v) {
    int x = (int)v;
    int t;
    t = __builtin_amdgcn_update_dpp(x, x, 0x111, 0xf, 0xf, false);
    x = (int)min((unsigned)x, (unsigned)t);
    t = __builtin_amdgcn_update_dpp(x, x, 0x112, 0xf, 0xf, false);
    x = (int)min((unsigned)x, (unsigned)t);
    t = __builtin_amdgcn_update_dpp(x, x, 0x114, 0xf, 0xf, false);
    x = (int)min((unsigned)x, (unsigned)t);
    t = __builtin_amdgcn_update_dpp(x, x, 0x118, 0xf, 0xf, false);
    x = (int)min((unsigned)x, (unsigned)t);
    t = __builtin_amdgcn_update_dpp(x, x, 0x142, 0xa, 0xf, false);
    x = (int)min((unsigned)x, (unsigned)t);
    t = __builtin_amdgcn_update_dpp(x, x, 0x143, 0xc, 0xf, false);
    x = (int)min((unsigned)x, (unsigned)t);
    return (unsigned)__builtin_amdgcn_readlane(x, 63);
}

// full-wave sum, total broadcast from lane 63
__device__ __forceinline__ float wave_sum_f32(float v) {
    float x = v;
    int t;
    t = __builtin_amdgcn_update_dpp(0, __float_as_int(x), 0x111, 0xf, 0xf, true);
    x += __int_as_float(t);
    t = __builtin_amdgcn_update_dpp(0, __float_as_int(x), 0x112, 0xf, 0xf, true);
    x += __int_as_float(t);
    t = __builtin_amdgcn_update_dpp(0, __float_as_int(x), 0x114, 0xf, 0xf, true);
    x += __int_as_float(t);
    t = __builtin_amdgcn_update_dpp(0, __float_as_int(x), 0x118, 0xf, 0xf, true);
    x += __int_as_float(t);
    t = __builtin_amdgcn_update_dpp(0, __float_as_int(x), 0x142, 0xa, 0xf, false);
    x += __int_as_float(t);
    t = __builtin_amdgcn_update_dpp(0, __float_as_int(x), 0x143, 0xc, 0xf, false);
    x += __int_as_float(t);
    return __int_as_float(__builtin_amdgcn_readlane(__float_as_int(x), 63));
}

// sum over each 8-lane group (quad xor1, xor2, row_half_mirror)
__device__ __forceinline__ float sum8_f32(float v) {
    float x = v;
    int t;
    t = __builtin_amdgcn_update_dpp(0, __float_as_int(x), 0xB1, 0xf, 0xf, false);
    x += __int_as_float(t);
    t = __builtin_amdgcn_update_dpp(0, __float_as_int(x), 0x4E, 0xf, 0xf, false);
    x += __int_as_float(t);
    t = __builtin_amdgcn_update_dpp(0, __float_as_int(x), 0x141, 0xf, 0xf, false);
    x += __int_as_float(t);
    return x;
}

// ---------------------------------------------------------------------------
// Kernel 1: G row + inline normalization; block 0 additionally writes
// Dn / DnT / acc (prep folded in; no separate init kernel).
__global__ void gram_kernel(const float* __restrict__ dict, float* __restrict__ ws) {
    float* G = ws + WS_G;
    int i = blockIdx.x, j = threadIdx.x;
    float sij = 0.f, sii = 0.f, sjj = 0.f;
    #pragma unroll
    for (int d = 0; d < DIM; ++d) {
        float a = dict[d*KAT + i];
        float b = dict[d*KAT + j];
        sij = fmaf(a, b, sij);
        sii = fmaf(a, a, sii);
        sjj = fmaf(b, b, sjj);
    }
    G[i*KAT + j] = sij / (sqrtf(sii) * sqrtf(sjj));

    if (i == 0) {                       // block 0: prep Dn/DnT + acc
        float* Dn  = ws + WS_DN;
        float* DnT = ws + WS_DNT;
        float* acc = ws + WS_ACC;
        if (j == 0) { acc[0] = 0.f; acc[1] = 0.f; ((unsigned*)acc)[2] = 0u; }
        float nrm = sqrtf(sjj);
        #pragma unroll
        for (int d = 0; d < DIM; ++d) {
            float v = dict[d*KAT + j] / nrm;
            Dn[d*KAT + j]  = v;
            DnT[j*DIM + d] = v;
        }
    }
}

// ---------------------------------------------------------------------------
// Kernel 2: fused zf-echo + gamma-zero + h_bar + Batch-OMP + finalize.
// 16 columns per 256-thread block, one wave per column, 4 columns/wave.
// Recon staged to ws_rec[n][d] (coalesced); permuted out by recon_kernel.
__global__ __launch_bounds__(256) void omp_kernel(const float* __restrict__ z_e,
                                                  const float* __restrict__ ws,
                                                  float* __restrict__ out,
                                                  const float* __restrict__ beta,
                                                  float* __restrict__ wsw) {
    const float* Dn  = ws + WS_DN;
    const float* DnT = ws + WS_DNT;
    const float* G   = ws + WS_G;
    float* acc = wsw + WS_ACC;
    float* wrec = wsw + WS_REC;

    __shared__ float xcols[DIM * 16];     // [d][c]   4 KB
    __shared__ float hbar[16 * KAT];      // [c][a]  32 KB

    const int t = threadIdx.x;
    const int n_base = blockIdx.x * 16;

    // ---- Phase 1: gather data columns; echo to zf output region
    #pragma unroll
    for (int i = 0; i < 4; ++i) {
        int e = t + i * 256;              // 0..1023
        int d = e >> 4, c = e & 15;
        int Lf = d * NCOL + n_base + c;
        int src = (Lf >> 16) * 65536 + (Lf & 63) * 1024 + (((Lf >> 11) & 31) << 5) + ((Lf >> 6) & 31);
        float v = z_e[src];
        xcols[e] = v;
        out[O_ZF + Lf] = v;
    }

    // ---- Phase 1.5: zero this block's gamma slice (gamma[a][n] only ever
    // written by the block owning n -> no separate 64MB init kernel needed).
    {
        float2* gz = (float2*)(out + O_GAMMA + n_base);
        float2 z2 = make_float2(0.f, 0.f);
        #pragma unroll
        for (int q = 0; q < 16; ++q) {
            int idx = q * 256 + t;        // 0..4095 = 512 atoms x 8 float2
            int a = idx >> 3, s = idx & 7;
            gz[(a * NCOL + s * 2) >> 1] = z2;
        }
    }
    __syncthreads();

    // ---- Phase 2: h_bar tile (Dn read once per block)
    {
        float a0[16], a1[16];
        #pragma unroll
        for (int i = 0; i < 16; ++i) { a0[i] = 0.f; a1[i] = 0.f; }
        const float4* xc4 = (const float4*)xcols;
        for (int d = 0; d < DIM; ++d) {
            float v0 = Dn[d * KAT + t];
            float v1 = Dn[d * KAT + 256 + t];
            #pragma unroll
            for (int q = 0; q < 4; ++q) {
                float4 xv = xc4[d * 4 + q];
                a0[q*4+0] = fmaf(v0, xv.x, a0[q*4+0]);
                a0[q*4+1] = fmaf(v0, xv.y, a0[q*4+1]);
                a0[q*4+2] = fmaf(v0, xv.z, a0[q*4+2]);
                a0[q*4+3] = fmaf(v0, xv.w, a0[q*4+3]);
                a1[q*4+0] = fmaf(v1, xv.x, a1[q*4+0]);
                a1[q*4+1] = fmaf(v1, xv.y, a1[q*4+1]);
                a1[q*4+2] = fmaf(v1, xv.z, a1[q*4+2]);
                a1[q*4+3] = fmaf(v1, xv.w, a1[q*4+3]);
            }
        }
        #pragma unroll
        for (int c = 0; c < 16; ++c) {
            hbar[c * KAT + t]       = a0[c];
            hbar[c * KAT + 256 + t] = a1[c];
        }
    }
    __syncthreads();

    // ---- Phase 3: OMP, one wave per column, 4 columns sequentially
    const int wv = t >> 6, lane = t & 63;
    float wv_sq = 0.f, wv_S = 0.f;

    #pragma unroll 1
    for (int cc = 0; cc < 4; ++cc) {
        const int col = wv * 4 + cc;
        const int n = n_base + col;
        const float* hbcol = hbar + col * KAT;

        float h[8];
        #pragma unroll
        for (int r = 0; r < 8; ++r) h[r] = hbcol[(r << 6) + lane];

        unsigned msk = 0;
        float uv[56];                 // u_0..u_6, uv[j*8+r]
        float Lr[28];                 // off-diag rows 1..7: Lr[i*(i-1)/2+j], j<i
        float invd[8], yv[8], xr[8];
        int Iv[8];

        #pragma unroll
        for (int k = 0; k < 8; ++k) {
            // local argmax over this lane's 8 slots (track signed winner)
            float bv = -1.f; int bi = 0; float hb = 0.f;
            #pragma unroll
            for (int r = 0; r < 8; ++r) {
                float av = ((msk >> r) & 1) ? -1.f : fabsf(h[r]);
                bool gt = av > bv;
                bv = gt ? av : bv;
                bi = gt ? ((r << 6) | lane) : bi;
                hb = gt ? h[r] : hb;
            }
            // wave max, then first-index among exact ties via u32 min
            float maxv = wave_max_bcast_f32(bv);
            unsigned cand = (bv == maxv) ? (unsigned)bi : 0xffffffffu;
            const int idx = __builtin_amdgcn_readfirstlane(
                                (int)wave_min_bcast_u32(cand));   // SGPR
            // signed winner h[idx] = +-maxv via one ballot
            unsigned long long sm = __ballot((bv == maxv) && (bi == idx) && (hb < 0.f));
            float hwin = (sm != 0ull) ? -maxv : maxv;

            if ((idx & 63) == lane) msk |= 1u << (idx >> 6);
            Iv[k] = idx;

            const float* grow = G + idx * KAT;   // scalar base -> saddr loads
            float gk[8];
            if (k < 7) {
                #pragma unroll
                for (int r = 0; r < 8; ++r) gk[r] = grow[(r << 6) + lane];
            }

            // replicated Cholesky rank-1 extension (uniform scalar loads)
            float Lk[7];
            if (k == 0) {
                invd[0] = 1.f;
            } else {
                float s2 = 0.f;
                #pragma unroll
                for (int i = 0; i < 7; ++i) if (i < k) {
                    float a = grow[Iv[i]];              // == G[Iv[i]][idx]
                    #pragma unroll
                    for (int j = 0; j < 7; ++j) if (j < i)
                        a = fmaf(-Lr[i*(i-1)/2 + j], Lk[j], a);
                    Lk[i] = a * invd[i];
                    s2 = fmaf(Lk[i], Lk[i], s2);
                }
                #pragma unroll
                for (int j = 0; j < 7; ++j) if (j < k) Lr[k*(k-1)/2 + j] = Lk[j];
                invd[k] = 1.f / sqrtf(1.f - s2);
            }
            yv[k] = hwin * invd[k];

            // u_k and incremental h update (not needed after last pick)
            if (k < 7) {
                #pragma unroll
                for (int r = 0; r < 8; ++r) {
                    float a = gk[r];
                    #pragma unroll
                    for (int j = 0; j < 7; ++j) if (j < k)
                        a = fmaf(-Lk[j], uv[j*8 + r], a);
                    a *= invd[k];
                    uv[k*8 + r] = a;
                    h[r] = fmaf(-yv[k], a, h[r]);
                }
            }
        }

        // single back solve: L^T xr = yv  (xr is lane-uniform)
        #pragma unroll
        for (int i = 7; i >= 0; --i) {
            float a = yv[i];
            #pragma unroll
            for (int j = 0; j < 8; ++j) if (j > i)
                a = fmaf(-Lr[j*(j-1)/2 + i], xr[j], a);
            xr[i] = a * invd[i];
        }

        // gamma scatter: one 8-lane store (xr/Iv uniform across lanes)
        {
            float gv = xr[0]; int ai = Iv[0];
            #pragma unroll
            for (int j = 1; j < 8; ++j) {
                bool m = (lane == j);
                gv = m ? xr[j] : gv;
                ai = m ? Iv[j] : ai;
            }
            if (lane < 8) out[O_GAMMA + ai * NCOL + n] = gv;
        }

        // recon (lane = d): coalesced store to ws_rec[n][d]
        float rec = 0.f;
        #pragma unroll
        for (int j = 0; j < 8; ++j)
            rec = fmaf(xr[j], DnT[Iv[j] * DIM + lane], rec);
        wrec[n * DIM + lane] = rec;

        // squared-error partial (DPP sum)
        float xd = xcols[lane * 16 + col];
        float diff = rec - xd;
        float sq = wave_sum_f32(diff * diff);
        if (lane == 0) wv_sq += sq;

        // softmax-entropy: 8 nnz + 504 zeros, parallel over lanes 0..7
        {
            float m = 0.f;
            #pragma unroll
            for (int j = 0; j < 8; ++j) m = fmaxf(m, xr[j]);
            float xsel = 0.f;
            #pragma unroll
            for (int j = 0; j < 8; ++j) xsel = (lane == j) ? xr[j] : xsel;
            float e = (lane < 8) ? __expf(xsel - m) : 0.f;
            float se = sum8_f32(e);
            float e0 = __expf(-m);
            float Z = fmaf(504.f, e0, se);       // valid on lanes 0..7
            float invZ = 1.f / Z;
            float p = e * invZ;
            float tq = (lane < 8) ? p * __logf(p + 1e-10f) : 0.f;
            tq = sum8_f32(tq);
            if (lane == 0) {
                float p0 = e0 * invZ;
                wv_S += tq + 504.f * p0 * __logf(p0 + 1e-10f);
            }
        }
    }

    if (lane == 0) {
        atomicAdd(&acc[0], wv_sq);
        atomicAdd(&acc[1], wv_S);
    }
    __threadfence();            // release: acc adds visible before counter bump
    __syncthreads();
    if (t == 0) {
        unsigned old = atomicAdd((unsigned*)acc + 2, 1u);
        if (old == gridDim.x - 1) {                 // last block finalizes
            __threadfence();                        // acquire
            float s0 = atomicAdd(&acc[0], 0.f);     // coherent L2 reads
            float s1 = atomicAdd(&acc[1], 0.f);
            float mse = s0 / 2097152.f;
            out[O_LOSS] = mse * 0.25f + beta[0] * mse;
            out[O_PERP] = __expf(-s1 / 32768.f);
        }
    }
}

// ---------------------------------------------------------------------------
// Kernel 3: recon permutation ws_rec[n][d] -> out[z_e layout], both coalesced.
// n = m*2048 + b10*1024 + j*64 + c0;  out addr = (d>>1)*65536 + c0*1024
//   + (((d&1)<<4)|m)*32 + (b10<<4) + j.  Tile: fixed (m,b10,c0g,dg), all j.
__global__ __launch_bounds__(256) void recon_kernel(const float* __restrict__ wsr,
                                                    float* __restrict__ out) {
    const float* rec = wsr + WS_REC;
    __shared__ float tile[16 * 16 * 16];   // [dd][c][j] 16 KB
    const int blk = blockIdx.x;            // 512 blocks
    const int dg  = blk & 3;
    const int c0g = (blk >> 2) & 3;
    const int b10 = (blk >> 4) & 1;
    const int m   = blk >> 5;              // 0..15
    const int t = threadIdx.x;

    // read phase: thread -> (j = t&15, c = t>>4), one n; 4 float4 = 16 d's
    {
        int j = t & 15, c = t >> 4;
        int n = m * 2048 + b10 * 1024 + j * 64 + c0g * 16 + c;
        const float4* src = (const float4*)(rec + n * DIM + dg * 16);
        #pragma unroll
        for (int q = 0; q < 4; ++q) {
            float4 v = src[q];
            tile[(q*4+0)*256 + c*16 + j] = v.x;
            tile[(q*4+1)*256 + c*16 + j] = v.y;
            tile[(q*4+2)*256 + c*16 + j] = v.z;
            tile[(q*4+3)*256 + c*16 + j] = v.w;
        }
    }
    __syncthreads();

    // write phase: i = dd; thread -> (c = t>>4, j = t&15); 16-float runs
    #pragma unroll
    for (int i = 0; i < 16; ++i) {
        int d = dg * 16 + i;
        float v = tile[i * 256 + t];
        int c0 = c0g * 16 + (t >> 4);
        int A = (d >> 1) * 65536 + c0 * 1024 + ((((d & 1) << 4) | m) << 5)
              + (b10 << 4) + (t & 15);
        out[O_RECON + A] = v;
    }
}

// ---------------------------------------------------------------------------
extern "C" void kernel_launch(void* const* d_in, const int* in_sizes, int n_in,
                              void* d_out, int out_size, void* d_ws, size_t ws_size,
                              hipStream_t stream) {
    const float* z_e  = (const float*)d_in[0];
    const float* dict = (const float*)d_in[1];
    const float* beta = (const float*)d_in[2];
    float* out = (float*)d_out;
    float* ws  = (float*)d_ws;

    gram_kernel<<<512, 512, 0, stream>>>(dict, ws);
    omp_kernel<<<2048, 256, 0, stream>>>(z_e, ws, out, beta, ws);
    recon_kernel<<<512, 256, 0, stream>>>(ws, out);
}